// Round 14
// baseline (390.492 us; speedup 1.0000x reference)
//
#include <hip/hip_runtime.h>
#include <hip/hip_bf16.h>
#include <cstdint>
#include <cstddef>

// Problem constants
static constexpr int B   = 1024;
static constexpr int N   = 64;
static constexpr int BN  = B * N;      // 65536 nodes
static constexpr int EPG = 192;
static constexpr int E   = B * EPG;    // 196608 edges
static constexpr int FP  = 608;        // padded feature dim (mult of 32)
static constexpr int KP1 = 320;        // conv1 K (PX0 cols, padded)
static constexpr int PMS = 80;         // Pm row stride (bf16)
static constexpr int NCONV = 2560;     // conv host blocks per conv dispatch
static constexpr int NG1  = 16;        // t1t2 guest blocks in conv1
static constexpr int NG2  = 384;       // EO guest blocks in conv2q

typedef __hip_bfloat16 bf16;
typedef __bf16 bf16x8 __attribute__((ext_vector_type(8)));
typedef __bf16 bf16x4 __attribute__((ext_vector_type(4)));
typedef float  f32x4  __attribute__((ext_vector_type(4)));

__device__ __forceinline__ void storeC(float* p, float v) { *p = v; }
__device__ __forceinline__ void storeC(bf16* p, float v) { *p = __float2bfloat16(v); }

// async global->LDS, 16B per lane; LDS dest is wave-uniform base + lane*16
__device__ __forceinline__ void llds16(const void* g, void* l) {
    __builtin_amdgcn_global_load_lds(
        (const __attribute__((address_space(1))) unsigned int*)g,
        (__attribute__((address_space(3))) unsigned int*)l,
        16, 0, 0);
}

// ===========================================================================
// 64x128 MFMA GEMM tile body: C[64 x 128 at (m0,n0)] = A @ Bt^T (+bias)(relu)
// (film).  4 waves each 64x32.  As: 4KB, Bs: 8KB.
// ===========================================================================
template<bool RELU, bool FILM, typename CT>
__device__ __forceinline__ void g64_tile(
    const bf16* __restrict__ A, int lda,
    const bf16* __restrict__ Bt, int ldb,
    const float* __restrict__ bias,
    CT* __restrict__ C, int ldc, int Ncap,
    const bf16* __restrict__ fS, const bf16* __restrict__ fT, int fstride,
    int K, int m0, int n0, __bf16* As, __bf16* Bs, int tid)
{
    const int lane = tid & 63;
    const int w    = tid >> 6;
    const int wn   = w * 32;
    const int l15  = lane & 15;
    const int lhi  = lane >> 4;

    f32x4 acc[4][2] = {};

    for (int k0 = 0; k0 < K; k0 += 32) {
        {   // A tile: 256 chunks of 16B, one per thread
            int row = tid >> 2, kc = tid & 3;
            char* la = (char*)As + (size_t)(w * 64) * 16;
            llds16(A + (size_t)(m0 + row) * lda + k0 + kc * 8, la);
        }
        #pragma unroll
        for (int t = 0; t < 2; ++t) {   // B tile: 512 chunks
            int ci  = t * 256 + tid;
            int row = ci >> 2, kc = ci & 3;
            char* lb = (char*)Bs + (size_t)(t * 256 + w * 64) * 16;
            llds16(Bt + (size_t)(n0 + row) * ldb + k0 + kc * 8, lb);
        }
        asm volatile("s_waitcnt vmcnt(0)" ::: "memory");
        __syncthreads();

        bf16x8 af[4], bg[2];
        #pragma unroll
        for (int i = 0; i < 4; ++i)
            af[i] = *(bf16x8*)(As + (i * 16 + l15) * 32 + lhi * 8);
        #pragma unroll
        for (int j = 0; j < 2; ++j)
            bg[j] = *(bf16x8*)(Bs + (wn + j * 16 + l15) * 32 + lhi * 8);
        #pragma unroll
        for (int i = 0; i < 4; ++i)
            #pragma unroll
            for (int j = 0; j < 2; ++j)
                acc[i][j] = __builtin_amdgcn_mfma_f32_16x16x32_bf16(
                    af[i], bg[j], acc[i][j], 0, 0, 0);
        __syncthreads();
    }

    #pragma unroll
    for (int i = 0; i < 4; ++i) {
        #pragma unroll
        for (int j = 0; j < 2; ++j) {
            int col = n0 + wn + j * 16 + l15;
            if (col < Ncap) {
                float bv = bias ? bias[col] : 0.f;
                #pragma unroll
                for (int e = 0; e < 4; ++e) {
                    int row = m0 + i * 16 + lhi * 4 + e;
                    float v = acc[i][j][e] + bv;
                    if (RELU) v = fmaxf(v, 0.f);
                    if (FILM) {
                        float sv = __bfloat162float(fS[(size_t)row * fstride + col]);
                        float tv = __bfloat162float(fT[(size_t)row * fstride + col]);
                        v = v * (1.f + sv) + tv;
                    }
                    storeC(&C[(size_t)row * ldc + col], v);
                }
            }
        }
    }
}

// ===========================================================================
// noinline guests (register isolation from host conv kernels — R9 lesson)
// ===========================================================================

// fused timestep MLP: A1b = relu(TE@Wt1t^T+b1) then A2b = relu(A1b@Wt2t^T+b2)
// for one 64-row slice; block-local RAW through global (same-CU write-through
// L1) separated by vmcnt(0)+barrier.
__device__ __attribute__((noinline)) void guest_t1t2(
    const bf16* TE, const bf16* Wt1t, const float* b_t1, bf16* A1b,
    const bf16* Wt2t, const float* b_t2, bf16* A2b,
    int t, char* lds, int tid)
{
    __bf16* As = (__bf16*)lds;
    __bf16* Bs = (__bf16*)(lds + 4096);
    int m0g = t * 64;
    #pragma unroll
    for (int nt2 = 0; nt2 < 4; ++nt2)
        g64_tile<true, false, bf16>(TE, 128, Wt1t, 128, b_t1, A1b, 512, 512,
                                    nullptr, nullptr, 0, 128,
                                    m0g, nt2 * 128, As, Bs, tid);
    asm volatile("s_waitcnt vmcnt(0)" ::: "memory");
    __syncthreads();
    #pragma unroll
    for (int nt2 = 0; nt2 < 4; ++nt2)
        g64_tile<true, false, bf16>(A1b, 512, Wt2t, 512, b_t2, A2b, 512, 512,
                                    nullptr, nullptr, 0, 512,
                                    m0g, nt2 * 128, As, Bs, tid);
}

// EO = A2b @ Wet^T + b_e (no relu), one 64x128 tile
__device__ __attribute__((noinline)) void guest_eo(
    const bf16* A2b, const bf16* Wet, const float* b_e, bf16* EO,
    int t, char* lds, int tid)
{
    int mt2 = t / 24, nt2 = t % 24;
    g64_tile<false, false, bf16>(A2b, 512, Wet, 512, b_e, EO, 3000, 3000,
                                 nullptr, nullptr, 0, 512,
                                 mt2 * 64, nt2 * 128,
                                 (__bf16*)lds, (__bf16*)(lds + 4096), tid);
}

// standalone 64-row-tile GEMM (h-layers)
template<bool RELU, bool FILM, typename CT>
__global__ __launch_bounds__(256) void gemm64(
    const bf16* __restrict__ A, int lda,
    const bf16* __restrict__ Bt, int ldb,
    const float* __restrict__ bias,
    CT* __restrict__ C, int ldc, int Ncap,
    const bf16* __restrict__ fS, const bf16* __restrict__ fT, int fstride,
    int K)
{
    __shared__ __align__(16) __bf16 As[64 * 32];
    __shared__ __align__(16) __bf16 Bs[128 * 32];
    g64_tile<RELU, FILM, CT>(A, lda, Bt, ldb, bias, C, ldc, Ncap,
                             fS, fT, fstride, K,
                             blockIdx.x * 64, blockIdx.y * 128, As, Bs,
                             threadIdx.x);
}

// G0 = Yv @ Wb3^T + b_c3 (80 blocks)
__global__ __launch_bounds__(256) void k_g0(
    const bf16* __restrict__ Yv, const bf16* __restrict__ Wb3,
    const float* __restrict__ b_c3, bf16* __restrict__ G0)
{
    __shared__ __align__(16) __bf16 As[64 * 32];
    __shared__ __align__(16) __bf16 Bs[128 * 32];
    int t = blockIdx.x;
    int mt = t / 5, nt = t % 5;
    g64_tile<false, false, bf16>(Yv, FP, Wb3, FP, b_c3, G0, FP, 600,
                                 nullptr, nullptr, 0, FP,
                                 mt * 64, nt * 128, As, Bs, threadIdx.x);
}

// ===========================================================================
// conv1 as a PLAIN GEMM (aggregation pre-commuted into PX0):
// X1 = relu(PX0 @ Wb1^T + b_c1).  + fused t1t2 guests (bid < NG1, run first).
// ===========================================================================
struct Conv1Args {
    const bf16* A; const bf16* Bt; const float* bias; bf16* X1;
    const bf16* TE; const bf16* Wt1t; const float* b_t1; bf16* A1b;
    const bf16* Wt2t; const float* b_t2; bf16* A2b;
};

__global__ __launch_bounds__(256) void conv1_gemm(Conv1Args a)
{
    __shared__ __align__(16) char regA[17408];
    const int tid = threadIdx.x;
    const int bid = blockIdx.x;

    if (bid < NG1) {
        guest_t1t2(a.TE, a.Wt1t, a.b_t1, a.A1b, a.Wt2t, a.b_t2, a.A2b,
                   bid, regA, tid);
        return;
    }
    const int hb = bid - NG1;

    __bf16* As = (__bf16*)regA;
    __bf16* Bs = (__bf16*)(regA + 8192);

    const int lane = tid & 63;
    const int w    = tid >> 6;
    const int wm   = (w & 1) * 64;
    const int wn   = (w >> 1) * 64;
    const int l15  = lane & 15;
    const int lhi  = lane >> 4;

    const int lid = hb >> 3;
    const int mt  = (hb & 7) * 64 + lid / 5;
    const int nt  = lid % 5;
    const int m0  = mt * 128;
    const int n0  = nt * 128;

    f32x4 acc[4][4] = {};
    for (int k0 = 0; k0 < KP1; k0 += 32) {
        #pragma unroll
        for (int t = 0; t < 2; ++t) {
            int ci  = t * 256 + w * 64 + lane;
            int row = ci >> 2, kc = ci & 3;
            char* la = (char*)regA + (size_t)(t * 256 + w * 64) * 16;
            char* lb = (char*)regA + 8192 + (size_t)(t * 256 + w * 64) * 16;
            llds16(a.A  + (size_t)(m0 + row) * KP1 + k0 + kc * 8, la);
            llds16(a.Bt + (size_t)(n0 + row) * KP1 + k0 + kc * 8, lb);
        }
        asm volatile("s_waitcnt vmcnt(0)" ::: "memory");
        __syncthreads();

        bf16x8 af[4], bg[4];
        #pragma unroll
        for (int i = 0; i < 4; ++i)
            af[i] = *(bf16x8*)(As + (wm + i * 16 + l15) * 32 + lhi * 8);
        #pragma unroll
        for (int j = 0; j < 4; ++j)
            bg[j] = *(bf16x8*)(Bs + (wn + j * 16 + l15) * 32 + lhi * 8);
        #pragma unroll
        for (int i = 0; i < 4; ++i)
            #pragma unroll
            for (int j = 0; j < 4; ++j)
                acc[i][j] = __builtin_amdgcn_mfma_f32_16x16x32_bf16(
                    af[i], bg[j], acc[i][j], 0, 0, 0);
        __syncthreads();
    }

    #pragma unroll
    for (int i = 0; i < 4; ++i)
        #pragma unroll
        for (int j = 0; j < 4; ++j) {
            int col = n0 + wn + j * 16 + l15;
            if (col < FP) {
                float bv = (col < 600) ? a.bias[col] : 0.f;
                #pragma unroll
                for (int e = 0; e < 4; ++e) {
                    int row = m0 + wm + i * 16 + lhi * 4 + e;
                    float v = fmaxf(acc[i][j][e] + bv, 0.f);
                    a.X1[(size_t)row * FP + col] = __float2bfloat16(v);
                }
            }
        }
}

// ===========================================================================
// conv2+conv3+pool fused.  P fragments direct from L2 (R13).  + EO guests
// (bid < NG2, run first; A2b produced in the previous dispatch).
// ===========================================================================
struct Conv2Args {
    const bf16* A; const bf16* Bt; const bf16* Pmg;
    const float* bias; const float* qv; bf16* Y;
    const bf16* A2b; const bf16* Wet; const float* b_e; bf16* EO;
};

__global__ __launch_bounds__(256) void conv_fused_q(Conv2Args a)
{
    __shared__ __align__(16) char regA[17408];
    __shared__ float s_q[128];

    const int tid = threadIdx.x;
    const int bid = blockIdx.x;

    if (bid < NG2) {
        guest_eo(a.A2b, a.Wet, a.b_e, a.EO, bid, regA, tid);
        return;
    }
    const int hb = bid - NG2;

    __bf16* As = (__bf16*)regA;
    __bf16* Bs = (__bf16*)(regA + 8192);
    __bf16* Ts = (__bf16*)regA;

    const int lane = tid & 63;
    const int w    = tid >> 6;
    const int wm   = (w & 1) * 64;
    const int wn   = (w >> 1) * 64;
    const int l15  = lane & 15;
    const int lhi  = lane >> 4;

    const int lid = hb >> 3;
    const int mt  = (hb & 7) * 64 + lid / 5;
    const int nt  = lid % 5;
    const int m0  = mt * 128;
    const int n0  = nt * 128;

    if (tid < 128) s_q[tid] = a.qv[mt * 128 + tid];

    f32x4 acc[4][4] = {};
    for (int k0 = 0; k0 < FP; k0 += 32) {
        #pragma unroll
        for (int t = 0; t < 2; ++t) {
            int ci  = t * 256 + w * 64 + lane;
            int row = ci >> 2, kc = ci & 3;
            char* la = (char*)regA + (size_t)(t * 256 + w * 64) * 16;
            char* lb = (char*)regA + 8192 + (size_t)(t * 256 + w * 64) * 16;
            llds16(a.A  + (size_t)(m0 + row) * FP + k0 + kc * 8, la);
            llds16(a.Bt + (size_t)(n0 + row) * FP + k0 + kc * 8, lb);
        }
        asm volatile("s_waitcnt vmcnt(0)" ::: "memory");
        __syncthreads();

        bf16x8 af[4], bg[4];
        #pragma unroll
        for (int i = 0; i < 4; ++i)
            af[i] = *(bf16x8*)(As + (wm + i * 16 + l15) * 32 + lhi * 8);
        #pragma unroll
        for (int j = 0; j < 4; ++j)
            bg[j] = *(bf16x8*)(Bs + (wn + j * 16 + l15) * 32 + lhi * 8);
        #pragma unroll
        for (int i = 0; i < 4; ++i)
            #pragma unroll
            for (int j = 0; j < 4; ++j)
                acc[i][j] = __builtin_amdgcn_mfma_f32_16x16x32_bf16(
                    af[i], bg[j], acc[i][j], 0, 0, 0);
        __syncthreads();
    }

    const bf16* Pbase = a.Pmg + (size_t)mt * (128 * PMS);
    const int g  = w & 1;
    const int nb = w >> 1;
    #pragma unroll
    for (int h = 0; h < 2; ++h) {
        if (wn == h * 64) {
            #pragma unroll
            for (int i = 0; i < 4; ++i)
                #pragma unroll
                for (int j = 0; j < 4; ++j) {
                    int c_local = j * 16 + l15;
                    int rbase   = wm + i * 16 + lhi * 4;
                    bf16x4 pk;
                    #pragma unroll
                    for (int e = 0; e < 4; ++e) pk[e] = (__bf16)acc[i][j][e];
                    *(bf16x4*)(Ts + c_local * 136 + rbase) = pk;
                }
        }
        __syncthreads();

        f32x4 acc2[4][2] = {};
        #pragma unroll
        for (int k0 = 0; k0 < 64; k0 += 32) {
            bf16x8 pa[4], hb2[2];
            #pragma unroll
            for (int i = 0; i < 4; ++i)
                pa[i] = *(const bf16x8*)((const __bf16*)Pbase
                          + (size_t)(g * 64 + i * 16 + l15) * PMS + k0 + lhi * 8);
            #pragma unroll
            for (int j = 0; j < 2; ++j)
                hb2[j] = *(bf16x8*)(Ts + (nb * 32 + j * 16 + l15) * 136
                                       + g * 64 + k0 + lhi * 8);
            #pragma unroll
            for (int i = 0; i < 4; ++i)
                #pragma unroll
                for (int j = 0; j < 2; ++j)
                    acc2[i][j] = __builtin_amdgcn_mfma_f32_16x16x32_bf16(
                        pa[i], hb2[j], acc2[i][j], 0, 0, 0);
        }
        #pragma unroll
        for (int j = 0; j < 2; ++j) {
            int col = n0 + h * 64 + nb * 32 + j * 16 + l15;
            float bv = (col < 600) ? a.bias[col] : 0.f;
            float yp = 0.f;
            #pragma unroll
            for (int i = 0; i < 4; ++i)
                #pragma unroll
                for (int e = 0; e < 4; ++e) {
                    float v = fmaxf(acc2[i][j][e] + bv, 0.f);   // relu
                    yp += s_q[g * 64 + i * 16 + lhi * 4 + e] * v;
                }
            yp += __shfl_xor(yp, 16, 64);
            yp += __shfl_xor(yp, 32, 64);
            if (lhi == 0 && col < FP)
                a.Y[(size_t)(mt * 2 + g) * FP + col] = __float2bfloat16(yp);
        }
        __syncthreads();
    }
}

// ===========================================================================
// Mega prep: [WT transposes | timestep emb | pair prep (Pmg,qv) | PX0 branch]
// ===========================================================================
struct WtJob  { const float* src; bf16* dst; int Ksrc, Nsrc, Kp, Np, blk0; };
struct PrepArgs {
    WtJob j[9];
    int nwt, te0, pp0, xtr0;
    const int*   ei;
    const float* ts;
    const float* xin; const float* Wtr; const float* btr; const float* mask;
    bf16* TE; bf16* Pmg; float* qv; bf16* PX0;
};

__global__ __launch_bounds__(256) void k_prep(PrepArgs a)
{
    __shared__ __align__(16) char sm[35840];
    const int bx  = blockIdx.x;
    const int tid = threadIdx.x;

    if (bx < a.nwt) {
        int ji = 0;
        while (ji < 8 && bx >= a.j[ji + 1].blk0) ++ji;
        WtJob jb = a.j[ji];
        int t  = bx - jb.blk0;
        int kt = (jb.Kp + 63) >> 6;
        int ti = t % kt, tj = t / kt;
        int kg0 = ti * 64, ng0 = tj * 64;
        float (*T)[65] = (float(*)[65])sm;
        #pragma unroll 4
        for (int r = 0; r < 16; ++r) {
            int kl = (tid >> 6) + r * 4, nl = tid & 63;
            int kg = kg0 + kl, ng = ng0 + nl;
            T[kl][nl] = (kg < jb.Ksrc && ng < jb.Nsrc)
                        ? jb.src[(size_t)kg * jb.Nsrc + ng] : 0.f;
        }
        __syncthreads();
        #pragma unroll 4
        for (int r = 0; r < 16; ++r) {
            int nl = (tid >> 6) + r * 4, kl = tid & 63;
            int ng = ng0 + nl, kg = kg0 + kl;
            if (ng < jb.Np && kg < jb.Kp)
                jb.dst[(size_t)ng * jb.Kp + kg] = __float2bfloat16(T[kl][nl]);
        }
    } else if (bx < a.pp0) {
        int idx = (bx - a.te0) * 256 + tid;
        int b = idx >> 7, jj = idx & 127;
        float tt = a.ts[b];
        int h = jj & 63;
        float freq = expf(-9.210340371976184f * (float)h / 64.f);  // ln(10000)
        float ang = tt * freq;
        a.TE[idx] = __float2bfloat16((jj < 64) ? cosf(ang) : sinf(ang));
    } else if (bx < a.xtr0) {
        // ---------- pair prep: P matrix (bf16, PMS stride) + q vector ----------
        int pr = bx - a.pp0;
        float* Pf   = (float*)sm;
        int*   cnt  = (int*)(sm + 32768);
        float* sQ   = (float*)(sm + 33280);
        float* sI   = (float*)(sm + 33792);
        float* sIvd = (float*)(sm + 34304);

        for (int idx = tid; idx < 8192; idx += 256) Pf[idx] = 0.f;
        if (tid < 128) cnt[tid] = 0;
        __syncthreads();
        for (int e = tid; e < 2 * EPG; e += 256) {
            int g  = (e >= EPG);
            int eg = (2 * pr + g) * EPG + (e - g * EPG);
            int ld = (a.ei[E + eg] & 63) + g * 64;
            atomicAdd(&cnt[ld], 1);
        }
        __syncthreads();
        if (tid < 128) {
            float d = (float)cnt[tid] + 1.0f;
            float iv = 1.f / d;
            sIvd[tid] = iv;
            sI[tid]   = rsqrtf(d);
            sQ[tid]   = iv;
        }
        __syncthreads();
        for (int e = tid; e < 2 * EPG; e += 256) {
            int g   = (e >= EPG);
            int eg  = (2 * pr + g) * EPG + (e - g * EPG);
            int lsl = a.ei[eg] & 63;
            int ldl = a.ei[E + eg] & 63;
            float cf = sI[g * 64 + lsl] * sI[g * 64 + ldl];
            atomicAdd(&Pf[(g * 64 + ldl) * 64 + lsl], cf);
            atomicAdd(&sQ[g * 64 + lsl], cf);
        }
        __syncthreads();
        if (tid < 128) {
            Pf[tid * 64 + (tid & 63)] += sIvd[tid];
            a.qv[pr * 128 + tid] = sQ[tid] * (1.f / 64.f);
        }
        __syncthreads();
        for (int idx = tid; idx < 128 * PMS; idx += 256) {
            int r = idx / PMS, k = idx - r * PMS;
            float v = (k < 64) ? Pf[r * 64 + k] : 0.f;
            a.Pmg[(size_t)pr * (128 * PMS) + idx] = __float2bfloat16(v);
        }
    } else {
        // ---------- PX0 branch (per graph): PX0 = xa@Wtr + ba*b^T ----------
        int g = bx - a.xtr0;
        float* Pf  = (float*)sm;                 // 64*64 fp32; Ws overlays later
        float* Ws  = (float*)sm;                 // 19*304 fp32
        float* xm  = (float*)(sm + 23104);       // 64*20 (col 19 = mask)
        float* xa  = (float*)(sm + 28224);       // 64*20 (col 19 = ba)
        float* isqv= (float*)(sm + 33344);
        float* ivdv= (float*)(sm + 33600);
        int*   cnt = (int*)  (sm + 33856);
        float* sb  = (float*)(sm + 34112);       // 304

        for (int idx = tid; idx < 4096; idx += 256) Pf[idx] = 0.f;
        if (tid < 64) cnt[tid] = 0;
        __syncthreads();
        if (tid < EPG) atomicAdd(&cnt[a.ei[E + g * EPG + tid] & 63], 1);
        __syncthreads();
        if (tid < 64) {
            float d = (float)cnt[tid] + 1.0f;
            ivdv[tid] = 1.f / d;
            isqv[tid] = rsqrtf(d);
        }
        __syncthreads();
        if (tid < EPG) {
            int ls = a.ei[g * EPG + tid] & 63;
            int ld = a.ei[E + g * EPG + tid] & 63;
            atomicAdd(&Pf[ld * 64 + ls], isqv[ls] * isqv[ld]);
        }
        for (int idx = tid; idx < 64 * 20; idx += 256) {
            int n = idx / 20, j = idx - n * 20;
            float mv = a.mask[g * 64 + n];
            xm[idx] = (j < 19) ? mv * a.xin[(size_t)(g * 64 + n) * 19 + j] : mv;
        }
        __syncthreads();
        if (tid < 64) Pf[tid * 64 + tid] += ivdv[tid];
        __syncthreads();
        for (int idx = tid; idx < 64 * 20; idx += 256) {
            int r = idx / 20, j = idx - r * 20;
            float s = 0.f;
            #pragma unroll 8
            for (int s2 = 0; s2 < 64; ++s2)
                s += Pf[r * 64 + s2] * xm[s2 * 20 + j];
            xa[idx] = s;
        }
        __syncthreads();
        for (int idx = tid; idx < 19 * 304; idx += 256) {
            int k = idx / 304, c = idx - k * 304;
            Ws[idx] = (c < 300) ? a.Wtr[k * 300 + c] : 0.f;
        }
        for (int c = tid; c < 304; c += 256)
            sb[c] = (c < 300) ? a.btr[c] : 0.f;
        __syncthreads();
        int n  = tid >> 2;
        int c0 = tid & 3;
        float ba = xa[n * 20 + 19];
        for (int c = c0; c < 304; c += 4) {
            float acc = ba * sb[c];
            #pragma unroll
            for (int k = 0; k < 19; ++k)
                acc += xa[n * 20 + k] * Ws[k * 304 + c];
            a.PX0[(size_t)(g * 64 + n) * KP1 + c] = __float2bfloat16(acc);
        }
        bf16x8 z = {};
        for (int idx = tid; idx < 64 * 2; idx += 256) {
            int nn = idx >> 1, jv = idx & 1;
            *(bf16x8*)((__bf16*)a.PX0 + (size_t)(g * 64 + nn) * KP1 + 304 + jv * 8) = z;
        }
    }
}

// LayerNorm over 300 dims + affine, fp32 out; fused text passthrough copy
__global__ __launch_bounds__(256) void k_ln_copy(const float* __restrict__ G,
                                                 const float* __restrict__ lg,
                                                 const float* __restrict__ lb,
                                                 const float* __restrict__ text,
                                                 float* __restrict__ out)
{
    int r = blockIdx.x;
    int tid = threadIdx.x;
    __shared__ float red[4];
    __shared__ float smu, svar;

    float v0 = (tid < 300) ? G[r * 300 + tid] : 0.f;
    float v1 = (tid + 256 < 300) ? G[r * 300 + tid + 256] : 0.f;
    float s = v0 + v1;
    #pragma unroll
    for (int o = 32; o > 0; o >>= 1) s += __shfl_down(s, o, 64);
    if ((tid & 63) == 0) red[tid >> 6] = s;
    __syncthreads();
    if (tid == 0) smu = (red[0] + red[1] + red[2] + red[3]) * (1.f / 300.f);
    __syncthreads();
    float mu = smu;
    float d0 = (tid < 300) ? v0 - mu : 0.f;
    float d1 = (tid + 256 < 300) ? v1 - mu : 0.f;
    s = d0 * d0 + d1 * d1;
    #pragma unroll
    for (int o = 32; o > 0; o >>= 1) s += __shfl_down(s, o, 64);
    if ((tid & 63) == 0) red[tid >> 6] = s;
    __syncthreads();
    if (tid == 0) svar = (red[0] + red[1] + red[2] + red[3]) * (1.f / 300.f);
    __syncthreads();
    float rstd = rsqrtf(svar + 1e-5f);
    if (tid < 300)
        out[r * 300 + tid] = d0 * rstd * lg[tid] + lb[tid];
    if (tid + 256 < 300)
        out[r * 300 + tid + 256] = d1 * rstd * lg[tid + 256] + lb[tid + 256];
    float* o2 = out + (size_t)B * 300;
    for (int c = tid; c < 300; c += 256)
        o2[(size_t)r * 300 + c] = text[(size_t)r * 300 + c];
}

// ---------------------------------------------------------------------------
extern "C" void kernel_launch(void* const* d_in, const int* in_sizes, int n_in,
                              void* d_out, int out_size, void* d_ws, size_t ws_size,
                              hipStream_t stream)
{
    const float* x_in  = (const float*)d_in[0];
    const int*   ei    = (const int*)d_in[1];
    const float* text  = (const float*)d_in[3];
    const float* tst   = (const float*)d_in[4];
    const float* mask  = (const float*)d_in[5];
    const float* W_tr  = (const float*)d_in[6];
    const float* b_tr  = (const float*)d_in[7];
    const float* W_c1  = (const float*)d_in[8];
    const float* b_c1  = (const float*)d_in[9];
    const float* W_c2  = (const float*)d_in[10];
    const float* b_c2  = (const float*)d_in[11];
    const float* W_c3  = (const float*)d_in[12];
    const float* b_c3  = (const float*)d_in[13];
    const float* W_h1  = (const float*)d_in[14];
    const float* b_h1  = (const float*)d_in[15];
    const float* W_h2  = (const float*)d_in[16];
    const float* b_h2  = (const float*)d_in[17];
    const float* W_h3  = (const float*)d_in[18];
    const float* b_h3  = (const float*)d_in[19];
    const float* ln_g  = (const float*)d_in[20];
    const float* ln_b  = (const float*)d_in[21];
    const float* W_t1  = (const float*)d_in[22];
    const float* b_t1  = (const float*)d_in[23];
    const float* W_t2  = (const float*)d_in[24];
    const float* b_t2  = (const float*)d_in[25];
    const float* W_e   = (const float*)d_in[26];
    const float* b_e   = (const float*)d_in[27];

    // workspace carve (256B aligned) — ~155 MB
    char* w = (char*)d_ws;
    size_t off = 0;
    auto carve = [&](size_t bytes) {
        void* p = w + off;
        off += (bytes + 255) & ~(size_t)255;
        return p;
    };
    bf16*  PX0    = (bf16*) carve((size_t)BN * KP1 * 2);     // 42 MB
    bf16*  X1     = (bf16*) carve((size_t)BN * FP * 2);      // 79.7 MB
    bf16*  Wb1    = (bf16*) carve((size_t)640 * KP1 * 2);
    bf16*  Wb2    = (bf16*) carve((size_t)640 * FP * 2);
    bf16*  Wb3    = (bf16*) carve((size_t)640 * FP * 2);
    bf16*  Wt1t   = (bf16*) carve((size_t)512 * 128 * 2);
    bf16*  Wt2t   = (bf16*) carve((size_t)512 * 512 * 2);
    bf16*  Wet    = (bf16*) carve((size_t)3072 * 512 * 2);
    bf16*  Wh1t   = (bf16*) carve((size_t)640 * FP * 2);
    bf16*  Wh2t   = (bf16*) carve((size_t)640 * FP * 2);
    bf16*  Wh3t   = (bf16*) carve((size_t)384 * FP * 2);
    bf16*  TE     = (bf16*) carve((size_t)B * 128 * 2);
    bf16*  A1b    = (bf16*) carve((size_t)B * 512 * 2);
    bf16*  A2b    = (bf16*) carve((size_t)B * 512 * 2);
    bf16*  EO     = (bf16*) carve((size_t)B * 3000 * 2);
    bf16*  Yv     = (bf16*) carve((size_t)B * FP * 2);
    bf16*  G0     = (bf16*) carve((size_t)B * FP * 2);
    bf16*  G1     = (bf16*) carve((size_t)B * FP * 2);
    bf16*  G2     = (bf16*) carve((size_t)B * FP * 2);
    float* G3     = (float*)carve((size_t)B * 300 * 4);
    bf16*  Pmg    = (bf16*) carve((size_t)512 * 128 * PMS * 2);  // 10.5 MB
    float* qv     = (float*)carve((size_t)BN * 4);
    (void)ws_size; (void)in_sizes; (void)n_in; (void)out_size;

    float* out = (float*)d_out;

    // --- dispatch 1: mega prep ---
    PrepArgs pa;
    struct JD { const float* s; bf16* d; int Ks, Ns, Kp, Np; };
    JD jd[9] = {
        { W_c1, Wb1,  300, 600,  KP1, 640 },
        { W_c2, Wb2,  600, 600,  FP,  640 },
        { W_c3, Wb3,  600, 600,  FP,  640 },
        { W_t1, Wt1t, 128, 512,  128, 512 },
        { W_t2, Wt2t, 512, 512,  512, 512 },
        { W_e,  Wet,  512, 3000, 512, 3072 },
        { W_h1, Wh1t, 600, 600,  FP,  640 },
        { W_h2, Wh2t, 600, 600,  FP,  640 },
        { W_h3, Wh3t, 600, 300,  FP,  384 },
    };
    int cum = 0;
    for (int i = 0; i < 9; ++i) {
        int kt = (jd[i].Kp + 63) >> 6, nt = (jd[i].Np + 63) >> 6;
        pa.j[i] = { jd[i].s, jd[i].d, jd[i].Ks, jd[i].Ns, jd[i].Kp, jd[i].Np, cum };
        cum += kt * nt;
    }
    pa.nwt  = cum;
    pa.te0  = cum;       cum += (B * 128) / 256;
    pa.pp0  = cum;       cum += B / 2;
    pa.xtr0 = cum;       cum += B;
    pa.ei = ei; pa.ts = tst;
    pa.xin = x_in; pa.Wtr = W_tr; pa.btr = b_tr; pa.mask = mask;
    pa.TE = TE; pa.Pmg = Pmg; pa.qv = qv; pa.PX0 = PX0;
    k_prep<<<cum, 256, 0, stream>>>(pa);

    // --- dispatch 2: conv1 plain GEMM + fused t1t2 guests (produce A2b) ---
    Conv1Args c1;
    c1.A = PX0; c1.Bt = Wb1; c1.bias = b_c1; c1.X1 = X1;
    c1.TE = TE; c1.Wt1t = Wt1t; c1.b_t1 = b_t1; c1.A1b = A1b;
    c1.Wt2t = Wt2t; c1.b_t2 = b_t2; c1.A2b = A2b;
    conv1_gemm<<<NG1 + NCONV, 256, 0, stream>>>(c1);

    // --- dispatch 3: conv2+conv3+pool + EO guests ---
    Conv2Args c2;
    c2.A = X1; c2.Bt = Wb2; c2.Pmg = Pmg; c2.bias = b_c2; c2.qv = qv; c2.Y = Yv;
    c2.A2b = A2b; c2.Wet = Wet; c2.b_e = b_e; c2.EO = EO;
    conv_fused_q<<<NG2 + NCONV, 256, 0, stream>>>(c2);

    // --- dispatch 4: G0 = Yv @ Wb3^T + b_c3 ---
    k_g0<<<80, 256, 0, stream>>>(Yv, Wb3, b_c3, G0);

    // --- h-layers with FiLM (64-row tiles) ---
    gemm64<true, true, bf16><<<dim3(16, 5), 256, 0, stream>>>(
        G0, FP, Wh1t, FP, b_h1, G1, FP, 600, EO + 0, EO + 600, 3000, FP);
    gemm64<true, true, bf16><<<dim3(16, 5), 256, 0, stream>>>(
        G1, FP, Wh2t, FP, b_h2, G2, FP, 600, EO + 1200, EO + 1800, 3000, FP);
    gemm64<false, true, float><<<dim3(16, 3), 256, 0, stream>>>(
        G2, FP, Wh3t, FP, b_h3, G3, 300, 300, EO + 2400, EO + 2700, 3000, FP);

    // --- layer norm + text passthrough ---
    k_ln_copy<<<B, 256, 0, stream>>>(G3, ln_g, ln_b, text, out);
}